// Round 1
// baseline (652.719 us; speedup 1.0000x reference)
//
#include <hip/hip_runtime.h>
#include <hip/hip_bf16.h>
#include <cstdint>

#define B_   4
#define S_   2048
#define E_   2048
#define H_   16
#define HKV_ 4
#define D_   128
#define KVD_ 512          // HKV_*D_
#define NQKV 3072         // E_ + 2*KVD_
// softmax scale folded into Q at projection time, in base-2 units:
// 1/sqrt(128) * log2(e)
#define QSCALE 0.1275253129f

typedef __bf16 bf16x8_t __attribute__((ext_vector_type(8)));
typedef float  f32x4_t  __attribute__((ext_vector_type(4)));

__device__ __forceinline__ ushort f2bf(float f) {
  uint32_t u = __builtin_bit_cast(uint32_t, f);
  uint32_t r = u + 0x7FFFu + ((u >> 16) & 1u);   // round-to-nearest-even
  return (ushort)(r >> 16);
}

__device__ __forceinline__ void gload16(const void* g, void* l) {
  __builtin_amdgcn_global_load_lds(
      (__attribute__((address_space(1))) void*)g,
      (__attribute__((address_space(3))) void*)l, 16, 0, 0);
}

// ---------------- x -> bf16 ----------------
__global__ __launch_bounds__(256) void k_cvt_x(const float* __restrict__ x,
                                               ushort* __restrict__ xb) {
  int i = blockIdx.x * 256 + threadIdx.x;          // 8 floats per thread
  const float4* p = (const float4*)x + (size_t)i * 2;
  float4 a = p[0], b = p[1];
  uint4 o;
  o.x = (uint32_t)f2bf(a.x) | ((uint32_t)f2bf(a.y) << 16);
  o.y = (uint32_t)f2bf(a.z) | ((uint32_t)f2bf(a.w) << 16);
  o.z = (uint32_t)f2bf(b.x) | ((uint32_t)f2bf(b.y) << 16);
  o.w = (uint32_t)f2bf(b.z) | ((uint32_t)f2bf(b.w) << 16);
  ((uint4*)xb)[i] = o;
}

// ------------- weight -> bf16, transposed: wb[n][k] = w[k][n] -------------
__global__ __launch_bounds__(256) void k_cvt_w_t(const float* __restrict__ w,
                                                 ushort* __restrict__ wb,
                                                 int C, int n_off) {
  __shared__ ushort t[32][33];
  int c0 = blockIdx.x * 32, r0 = blockIdx.y * 32;
  int tx = threadIdx.x, ty = threadIdx.y;          // 32 x 8
#pragma unroll
  for (int i = 0; i < 4; ++i) {
    int r = ty + i * 8;
    t[r][tx] = f2bf(w[(size_t)(r0 + r) * C + c0 + tx]);
  }
  __syncthreads();
#pragma unroll
  for (int i = 0; i < 4; ++i) {
    int c = ty + i * 8;
    wb[(size_t)(n_off + c0 + c) * E_ + r0 + tx] = t[tx][c];
  }
}

// ------------- fused QKV projection GEMM (m97 structure) -------------
// C[8192][3072] = xb[8192][2048] @ wb^T (wb is [3072][2048] = W[n][k])
// epilogue: +bias, +pos_emb (Q,K), *QSCALE (Q only), -> bf16 qkv
__global__ __launch_bounds__(256) void k_gemm(
    const ushort* __restrict__ xb, const ushort* __restrict__ wb,
    const float* __restrict__ wq_b, const float* __restrict__ wk_b,
    const float* __restrict__ wv_b, const float* __restrict__ pos,
    ushort* __restrict__ qkv) {
  __shared__ ushort As[128 * 64];
  __shared__ ushort Bs[128 * 64];
  int tid = threadIdx.x;
  int wid = tid >> 6, lane = tid & 63;
  int l15 = lane & 15, l4 = lane >> 4;
  int wr = wid >> 1, wc = wid & 1;
  int m0 = blockIdx.y * 128, n0 = blockIdx.x * 128;
  f32x4_t acc[4][4] = {};

  for (int k0 = 0; k0 < E_; k0 += 64) {
#pragma unroll
    for (int it = 0; it < 4; ++it) {
      int p = it * 256 + tid;
      int row = p >> 3, c = p & 7;
      gload16(xb + (size_t)(m0 + row) * E_ + k0 + c * 8,
              (char*)As + (size_t)(it * 256 + wid * 64) * 16);
      gload16(wb + (size_t)(n0 + row) * E_ + k0 + c * 8,
              (char*)Bs + (size_t)(it * 256 + wid * 64) * 16);
    }
    __syncthreads();
#pragma unroll
    for (int kk = 0; kk < 2; ++kk) {
      bf16x8_t a[4], b[4];
#pragma unroll
      for (int mi = 0; mi < 4; ++mi)
        a[mi] = *(const bf16x8_t*)&As[(wr * 64 + mi * 16 + l15) * 64 + kk * 32 + l4 * 8];
#pragma unroll
      for (int ni = 0; ni < 4; ++ni)
        b[ni] = *(const bf16x8_t*)&Bs[(wc * 64 + ni * 16 + l15) * 64 + kk * 32 + l4 * 8];
#pragma unroll
      for (int mi = 0; mi < 4; ++mi)
#pragma unroll
        for (int ni = 0; ni < 4; ++ni)
          acc[mi][ni] = __builtin_amdgcn_mfma_f32_16x16x32_bf16(
              a[mi], b[ni], acc[mi][ni], 0, 0, 0);
    }
    __syncthreads();
  }
  // epilogue
#pragma unroll
  for (int mi = 0; mi < 4; ++mi) {
#pragma unroll
    for (int ni = 0; ni < 4; ++ni) {
      int n = n0 + wc * 64 + ni * 16 + l15;
      int mbase = m0 + wr * 64 + mi * 16 + l4 * 4;
#pragma unroll
      for (int r = 0; r < 4; ++r) {
        int m = mbase + r;
        int srow = m & (S_ - 1);
        float v = acc[mi][ni][r];
        if (n < E_)
          v = (v + wq_b[n] + pos[(size_t)srow * E_ + n]) * QSCALE;
        else if (n < E_ + KVD_)
          v = v + wk_b[n - E_] + pos[(size_t)srow * E_ + (n - E_)];
        else
          v = v + wv_b[n - E_ - KVD_];
        qkv[(size_t)m * NQKV + n] = f2bf(v);
      }
    }
  }
}

// ------------- V transpose: vt[(b*4+kh)*128 + d][s] = V[b][s][kh][d] -------------
__global__ __launch_bounds__(256) void k_v_t(const ushort* __restrict__ qkv,
                                             ushort* __restrict__ vt) {
  __shared__ ushort t[32][33];
  int b = blockIdx.z >> 2, kh = blockIdx.z & 3;
  int s0 = blockIdx.x * 32, d0 = blockIdx.y * 32;
  int tx = threadIdx.x, ty = threadIdx.y;
#pragma unroll
  for (int i = 0; i < 4; ++i) {
    int s = s0 + ty + i * 8;
    t[ty + i * 8][tx] =
        qkv[(size_t)(b * S_ + s) * NQKV + E_ + KVD_ + kh * D_ + d0 + tx];
  }
  __syncthreads();
#pragma unroll
  for (int i = 0; i < 4; ++i) {
    int d = d0 + ty + i * 8;
    vt[(size_t)((b * HKV_ + kh) * D_ + d) * S_ + s0 + tx] = t[tx][ty + i * 8];
  }
}

// ------------- flash attention (non-causal, GQA) -------------
// grid (S/64, B*H); 4 waves/WG, each wave owns 16 q rows.
__global__ __launch_bounds__(256) void k_attn(const ushort* __restrict__ qkv,
                                              const ushort* __restrict__ vt,
                                              float* __restrict__ out) {
  __shared__ ushort Ks[64 * 128];   // [key][d], XOR-swizzled chunks
  __shared__ ushort Vs[128 * 64];   // [d][key], XOR-swizzled chunks
  __shared__ ushort Pl[4][16 * 72]; // per-wave P tile, padded rows
  int tid = threadIdx.x, wid = tid >> 6, lane = tid & 63;
  int l15 = lane & 15, l4 = lane >> 4;
  int qb = blockIdx.x, bh = blockIdx.y;
  int b = bh >> 4, h = bh & 15, kh = h >> 2;
  int qrow0 = qb * 64 + wid * 16;

  // Q fragments (scale already folded in at projection)
  bf16x8_t qf[4];
  {
    const ushort* qg = qkv + (size_t)(b * S_ + qrow0 + l15) * NQKV + h * D_;
#pragma unroll
    for (int c = 0; c < 4; ++c)
      qf[c] = *(const bf16x8_t*)(qg + c * 32 + l4 * 8);
  }

  f32x4_t ao[8] = {};
  float mrow[4] = {-1e30f, -1e30f, -1e30f, -1e30f};
  float lrow[4] = {0.f, 0.f, 0.f, 0.f};

  const ushort* kbase = qkv + (size_t)b * S_ * NQKV + E_ + kh * D_;
  const ushort* vbase = vt + (size_t)(b * HKV_ + kh) * D_ * S_;

  for (int t = 0; t < S_ / 64; ++t) {
    int key0 = t * 64;
#pragma unroll
    for (int it = 0; it < 4; ++it) {
      int p = it * 256 + tid;
      // K: rows of 256B = 16 chunks; swizzle low 3 bits of chunk with row
      int kr = p >> 4, c0 = p & 15;
      int c = (c0 & 8) | ((c0 ^ kr) & 7);
      gload16(kbase + (size_t)(key0 + kr) * NQKV + c * 8,
              (char*)Ks + (size_t)(it * 256 + wid * 64) * 16);
      // V^T: rows of 128B = 8 chunks
      int dr = p >> 3, cv0 = p & 7;
      int cv = (cv0 ^ dr) & 7;
      gload16(vbase + (size_t)dr * S_ + key0 + cv * 8,
              (char*)Vs + (size_t)(it * 256 + wid * 64) * 16);
    }
    __syncthreads();

    // QK^T: scores 16q x 64keys per wave
    f32x4_t sc[4] = {};
#pragma unroll
    for (int kt = 0; kt < 4; ++kt) {
      int key = kt * 16 + l15;
#pragma unroll
      for (int c = 0; c < 4; ++c) {
        int chunk = c * 4 + l4;
        int sw = (chunk & 8) | ((chunk ^ key) & 7);
        bf16x8_t kf = *(const bf16x8_t*)&Ks[key * 128 + sw * 8];
        sc[kt] = __builtin_amdgcn_mfma_f32_16x16x32_bf16(qf[c], kf, sc[kt], 0, 0, 0);
      }
    }

    // online softmax (base-2; scale folded into Q)
    float pr[4][4];
#pragma unroll
    for (int r = 0; r < 4; ++r) {
      float tmax = fmaxf(fmaxf(sc[0][r], sc[1][r]), fmaxf(sc[2][r], sc[3][r]));
      tmax = fmaxf(tmax, __shfl_xor(tmax, 1));
      tmax = fmaxf(tmax, __shfl_xor(tmax, 2));
      tmax = fmaxf(tmax, __shfl_xor(tmax, 4));
      tmax = fmaxf(tmax, __shfl_xor(tmax, 8));
      float mnew = fmaxf(mrow[r], tmax);
      float f = __builtin_amdgcn_exp2f(mrow[r] - mnew);
      float rs = 0.f;
#pragma unroll
      for (int kt = 0; kt < 4; ++kt) {
        float pv = __builtin_amdgcn_exp2f(sc[kt][r] - mnew);
        pr[kt][r] = pv;
        rs += pv;
      }
      rs += __shfl_xor(rs, 1);
      rs += __shfl_xor(rs, 2);
      rs += __shfl_xor(rs, 4);
      rs += __shfl_xor(rs, 8);
      lrow[r] = lrow[r] * f + rs;
      mrow[r] = mnew;
#pragma unroll
      for (int dt = 0; dt < 8; ++dt) ao[dt][r] *= f;
    }

    // P -> LDS (C-layout write), re-read in A-layout (padded stride kills conflicts)
    ushort* pl = &Pl[wid][0];
#pragma unroll
    for (int kt = 0; kt < 4; ++kt)
#pragma unroll
      for (int r = 0; r < 4; ++r)
        pl[(l4 * 4 + r) * 72 + kt * 16 + l15] = f2bf(pr[kt][r]);
    bf16x8_t pa[2];
#pragma unroll
    for (int kk = 0; kk < 2; ++kk)
      pa[kk] = *(const bf16x8_t*)&pl[l15 * 72 + kk * 32 + l4 * 8];

    // PV: out 16q x 128d per wave
#pragma unroll
    for (int dt = 0; dt < 8; ++dt) {
      int d = dt * 16 + l15;
#pragma unroll
      for (int kk = 0; kk < 2; ++kk) {
        int chunk = kk * 4 + l4;
        int sw = (chunk ^ d) & 7;
        bf16x8_t vf = *(const bf16x8_t*)&Vs[d * 64 + sw * 8];
        ao[dt] = __builtin_amdgcn_mfma_f32_16x16x32_bf16(pa[kk], vf, ao[dt], 0, 0, 0);
      }
    }
    __syncthreads();
  }

  // epilogue: out[b][q][h*128+d] = ao / l
#pragma unroll
  for (int r = 0; r < 4; ++r) {
    float rinv = 1.0f / lrow[r];
    int q = qrow0 + l4 * 4 + r;
    float* og = out + (size_t)(b * S_ + q) * E_ + h * D_;
#pragma unroll
    for (int dt = 0; dt < 8; ++dt) og[dt * 16 + l15] = ao[dt][r] * rinv;
  }
}

extern "C" void kernel_launch(void* const* d_in, const int* in_sizes, int n_in,
                              void* d_out, int out_size, void* d_ws, size_t ws_size,
                              hipStream_t stream) {
  const float* x    = (const float*)d_in[0];
  const float* wq_w = (const float*)d_in[1];
  const float* wq_b = (const float*)d_in[2];
  const float* wk_w = (const float*)d_in[3];
  const float* wk_b = (const float*)d_in[4];
  const float* wv_w = (const float*)d_in[5];
  const float* wv_b = (const float*)d_in[6];
  const float* pos  = (const float*)d_in[7];
  float* out = (float*)d_out;

  // scratch layout:
  //   d_out (64MB) doubles as conversion scratch before attention overwrites it:
  //     xb  [8192][2048] bf16 @ 0          (33,554,432 B)
  //     wb  [3072][2048] bf16 @ 33,554,432 (12,582,912 B)  -> 46.1 MB < 64 MB
  //   d_ws:
  //     qkv [8192][3072] bf16 @ 0          (50,331,648 B)
  //     vt  [16][128][2048] bf16 @ 50,331,648 (8,388,608 B) -> needs ws >= 58.7 MB
  ushort* xb  = (ushort*)d_out;
  ushort* wb  = (ushort*)((char*)d_out + 33554432);
  ushort* qkv = (ushort*)d_ws;
  ushort* vt  = (ushort*)((char*)d_ws + 50331648);

  k_cvt_x<<<dim3((B_ * S_ * E_) / 8 / 256), 256, 0, stream>>>(x, xb);
  dim3 tb(32, 8);
  k_cvt_w_t<<<dim3(E_ / 32, E_ / 32), tb, 0, stream>>>(wq_w, wb, E_, 0);
  k_cvt_w_t<<<dim3(KVD_ / 32, E_ / 32), tb, 0, stream>>>(wk_w, wb, KVD_, E_);
  k_cvt_w_t<<<dim3(KVD_ / 32, E_ / 32), tb, 0, stream>>>(wv_w, wb, KVD_, E_ + KVD_);
  k_gemm<<<dim3(NQKV / 128, (B_ * S_) / 128), 256, 0, stream>>>(
      xb, wb, wq_b, wk_b, wv_b, pos, qkv);
  k_v_t<<<dim3(S_ / 32, D_ / 32, B_ * HKV_), tb, 0, stream>>>(qkv, vt);
  k_attn<<<dim3(S_ / 64, B_ * H_), 256, 0, stream>>>(qkv, vt, out);
}

// Round 2
// 486.031 us; speedup vs baseline: 1.3430x; 1.3430x over previous
//
#include <hip/hip_runtime.h>
#include <hip/hip_bf16.h>
#include <cstdint>

#define B_   4
#define S_   2048
#define E_   2048
#define H_   16
#define HKV_ 4
#define D_   128
#define KVD_ 512          // HKV_*D_
#define NQKV 3072         // E_ + 2*KVD_
// softmax scale folded into Q at projection time, in base-2 units:
// 1/sqrt(128) * log2(e)
#define QSCALE 0.1275253129f

typedef __bf16 bf16x8_t __attribute__((ext_vector_type(8)));
typedef float  f32x4_t  __attribute__((ext_vector_type(4)));
typedef float  f32x16_t __attribute__((ext_vector_type(16)));

__device__ __forceinline__ ushort f2bf(float f) {
  uint32_t u = __builtin_bit_cast(uint32_t, f);
  uint32_t r = u + 0x7FFFu + ((u >> 16) & 1u);   // round-to-nearest-even
  return (ushort)(r >> 16);
}

__device__ __forceinline__ void gload16(const void* g, void* l) {
  __builtin_amdgcn_global_load_lds(
      (__attribute__((address_space(1))) void*)g,
      (__attribute__((address_space(3))) void*)l, 16, 0, 0);
}

__device__ __forceinline__ uint32_t cvtpk(float lo, float hi) {
  uint32_t r;
  asm volatile("v_cvt_pk_bf16_f32 %0, %1, %2" : "=v"(r) : "v"(lo), "v"(hi));
  return r;
}

__device__ __forceinline__ void plswap(uint32_t& a, uint32_t& b) {
  asm volatile("v_permlane32_swap_b32 %0, %1" : "+v"(a), "+v"(b));
}

// ---------------- x -> bf16 ----------------
__global__ __launch_bounds__(256) void k_cvt_x(const float* __restrict__ x,
                                               ushort* __restrict__ xb) {
  int i = blockIdx.x * 256 + threadIdx.x;          // 8 floats per thread
  const float4* p = (const float4*)x + (size_t)i * 2;
  float4 a = p[0], b = p[1];
  uint4 o;
  o.x = (uint32_t)f2bf(a.x) | ((uint32_t)f2bf(a.y) << 16);
  o.y = (uint32_t)f2bf(a.z) | ((uint32_t)f2bf(a.w) << 16);
  o.z = (uint32_t)f2bf(b.x) | ((uint32_t)f2bf(b.y) << 16);
  o.w = (uint32_t)f2bf(b.z) | ((uint32_t)f2bf(b.w) << 16);
  ((uint4*)xb)[i] = o;
}

// ------------- weight -> bf16, transposed: wb[n][k] = w[k][n] -------------
__global__ __launch_bounds__(256) void k_cvt_w_t(const float* __restrict__ w,
                                                 ushort* __restrict__ wb,
                                                 int C, int n_off) {
  __shared__ ushort t[32][33];
  int c0 = blockIdx.x * 32, r0 = blockIdx.y * 32;
  int tx = threadIdx.x, ty = threadIdx.y;          // 32 x 8
#pragma unroll
  for (int i = 0; i < 4; ++i) {
    int r = ty + i * 8;
    t[r][tx] = f2bf(w[(size_t)(r0 + r) * C + c0 + tx]);
  }
  __syncthreads();
#pragma unroll
  for (int i = 0; i < 4; ++i) {
    int c = ty + i * 8;
    wb[(size_t)(n_off + c0 + c) * E_ + r0 + tx] = t[tx][c];
  }
}

// ------------- fused QKV projection GEMM (m97 structure) -------------
__global__ __launch_bounds__(256) void k_gemm(
    const ushort* __restrict__ xb, const ushort* __restrict__ wb,
    const float* __restrict__ wq_b, const float* __restrict__ wk_b,
    const float* __restrict__ wv_b, const float* __restrict__ pos,
    ushort* __restrict__ qkv) {
  __shared__ ushort As[128 * 64];
  __shared__ ushort Bs[128 * 64];
  int tid = threadIdx.x;
  int wid = tid >> 6, lane = tid & 63;
  int l15 = lane & 15, l4 = lane >> 4;
  int wr = wid >> 1, wc = wid & 1;
  int m0 = blockIdx.y * 128, n0 = blockIdx.x * 128;
  f32x4_t acc[4][4] = {};

  for (int k0 = 0; k0 < E_; k0 += 64) {
#pragma unroll
    for (int it = 0; it < 4; ++it) {
      int p = it * 256 + tid;
      int row = p >> 3, c = p & 7;
      gload16(xb + (size_t)(m0 + row) * E_ + k0 + c * 8,
              (char*)As + (size_t)(it * 256 + wid * 64) * 16);
      gload16(wb + (size_t)(n0 + row) * E_ + k0 + c * 8,
              (char*)Bs + (size_t)(it * 256 + wid * 64) * 16);
    }
    __syncthreads();
#pragma unroll
    for (int kk = 0; kk < 2; ++kk) {
      bf16x8_t a[4], b[4];
#pragma unroll
      for (int mi = 0; mi < 4; ++mi)
        a[mi] = *(const bf16x8_t*)&As[(wr * 64 + mi * 16 + l15) * 64 + kk * 32 + l4 * 8];
#pragma unroll
      for (int ni = 0; ni < 4; ++ni)
        b[ni] = *(const bf16x8_t*)&Bs[(wc * 64 + ni * 16 + l15) * 64 + kk * 32 + l4 * 8];
#pragma unroll
      for (int mi = 0; mi < 4; ++mi)
#pragma unroll
        for (int ni = 0; ni < 4; ++ni)
          acc[mi][ni] = __builtin_amdgcn_mfma_f32_16x16x32_bf16(
              a[mi], b[ni], acc[mi][ni], 0, 0, 0);
    }
    __syncthreads();
  }
#pragma unroll
  for (int mi = 0; mi < 4; ++mi) {
#pragma unroll
    for (int ni = 0; ni < 4; ++ni) {
      int n = n0 + wc * 64 + ni * 16 + l15;
      int mbase = m0 + wr * 64 + mi * 16 + l4 * 4;
#pragma unroll
      for (int r = 0; r < 4; ++r) {
        int m = mbase + r;
        int srow = m & (S_ - 1);
        float v = acc[mi][ni][r];
        if (n < E_)
          v = (v + wq_b[n] + pos[(size_t)srow * E_ + n]) * QSCALE;
        else if (n < E_ + KVD_)
          v = v + wk_b[n - E_] + pos[(size_t)srow * E_ + (n - E_)];
        else
          v = v + wv_b[n - E_ - KVD_];
        qkv[(size_t)m * NQKV + n] = f2bf(v);
      }
    }
  }
}

// ------------- V transpose: vt[(b*4+kh)*128 + d][s] = V[b][s][kh][d] -------------
__global__ __launch_bounds__(256) void k_v_t(const ushort* __restrict__ qkv,
                                             ushort* __restrict__ vt) {
  __shared__ ushort t[32][33];
  int b = blockIdx.z >> 2, kh = blockIdx.z & 3;
  int s0 = blockIdx.x * 32, d0 = blockIdx.y * 32;
  int tx = threadIdx.x, ty = threadIdx.y;
#pragma unroll
  for (int i = 0; i < 4; ++i) {
    int s = s0 + ty + i * 8;
    t[ty + i * 8][tx] =
        qkv[(size_t)(b * S_ + s) * NQKV + E_ + KVD_ + kh * D_ + d0 + tx];
  }
  __syncthreads();
#pragma unroll
  for (int i = 0; i < 4; ++i) {
    int d = d0 + ty + i * 8;
    vt[(size_t)((b * HKV_ + kh) * D_ + d) * S_ + s0 + tx] = t[tx][ty + i * 8];
  }
}

// ------------- flash attention: m214-style 8-wave 32x32 swapped-QK -------------
// grid (S/256, B*H); 8 waves/WG, each wave owns 32 q rows; KVBLK=64.
// K LDS [64 key][128 d] bf16, XOR-swizzled (elem off ^= (row&7)<<3)
// V LDS [128 d][64 key] bf16, XOR-swizzled same
__global__ __launch_bounds__(512, 2) void k_attn(const ushort* __restrict__ qkv,
                                                 const ushort* __restrict__ vt,
                                                 float* __restrict__ out) {
  __shared__ char lds[2][32768];   // per buf: Ks 16KB @0, Vs 16KB @16384
  int tid = threadIdx.x, wid = tid >> 6, lane = tid & 63;
  int l31 = lane & 31, hi = lane >> 5;
  int bh = blockIdx.y;
  int b = bh >> 4, h = bh & 15, kh = h >> 2;
  int qw0 = blockIdx.x * 256 + wid * 32;

  // Q fragments: lane holds Q[q=qw0+l31][k*16 + hi*8 + j] (scale pre-folded)
  bf16x8_t qf[8];
  {
    const ushort* qg = qkv + (size_t)(b * S_ + qw0 + l31) * NQKV + h * D_ + hi * 8;
#pragma unroll
    for (int k = 0; k < 8; ++k) qf[k] = *(const bf16x8_t*)(qg + k * 16);
  }

  const ushort* kbase = qkv + (size_t)b * S_ * NQKV + E_ + kh * D_;
  const ushort* vbase = vt + (size_t)(b * HKV_ + kh) * D_ * S_;

  // staging coords (2 insts each for K and V per thread)
  int rk0 = wid * 4 + (lane >> 4);            // K row, inst i adds 32
  int dk0 = ((lane & 15) * 8);                // K col elems, pre-swizzle
  int dv0 = wid * 8 + (lane >> 3);            // V row (d), inst i adds 64
  int kv0 = ((lane & 7) * 8);                 // V col elems, pre-swizzle

  f32x16_t ao[4] = {};
  float mrow = -1e30f, lsum = 0.f;

#define STAGE(key0, bufp)                                                      \
  {                                                                            \
    char* bp_ = (bufp);                                                        \
    _Pragma("unroll")                                                          \
    for (int i = 0; i < 2; ++i) {                                              \
      int rk = i * 32 + rk0;                                                   \
      int dk = dk0 ^ ((rk & 7) << 3);                                          \
      gload16(kbase + (size_t)((key0) + rk) * NQKV + dk,                       \
              bp_ + i * 8192 + wid * 1024);                                    \
      int dv = i * 64 + dv0;                                                   \
      int kv = kv0 ^ ((dv & 7) << 3);                                          \
      gload16(vbase + (size_t)dv * S_ + (key0) + kv,                           \
              bp_ + 16384 + i * 8192 + wid * 1024);                            \
    }                                                                          \
  }

  STAGE(0, lds[0]);
  __syncthreads();

  int cur = 0;
  const int nt = S_ / 64;
  for (int t = 0; t < nt; ++t) {
    if (t + 1 < nt) STAGE((t + 1) * 64, lds[cur ^ 1]);

    const ushort* Ks = (const ushort*)(lds[cur]);
    const ushort* Vs = (const ushort*)(lds[cur] + 16384);

    // QK^T swapped: sc[kb] = K(32key x 128d) . Q^T -> P^T[key][q], col=q=l31
    f32x16_t sc[2] = {};
#pragma unroll
    for (int kb = 0; kb < 2; ++kb) {
      int row = kb * 32 + l31;
      const ushort* kr = Ks + row * 128;
      int sw = (l31 & 7) << 3;
#pragma unroll
      for (int ks = 0; ks < 8; ++ks) {
        bf16x8_t kf = *(const bf16x8_t*)(kr + ((ks * 16 + hi * 8) ^ sw));
        sc[kb] = __builtin_amdgcn_mfma_f32_32x32x16_bf16(kf, qf[ks], sc[kb], 0, 0, 0);
      }
    }

    // online softmax: lane's 32 sc values all belong to q = l31
    float tmax = sc[0][0];
#pragma unroll
    for (int r = 1; r < 16; ++r) tmax = fmaxf(tmax, sc[0][r]);
#pragma unroll
    for (int r = 0; r < 16; ++r) tmax = fmaxf(tmax, sc[1][r]);
    tmax = fmaxf(tmax, __shfl_xor(tmax, 32));

    // defer-max (T13): only rescale when growth exceeds 8 (log2 units)
    if (!__all(tmax - mrow <= 8.f)) {
      float mnew = fmaxf(mrow, tmax);
      float f = __builtin_amdgcn_exp2f(mrow - mnew);
      mrow = mnew;
      lsum *= f;
#pragma unroll
      for (int r = 0; r < 16; ++r) {
        float fr = __shfl(f, (r & 3) + 8 * (r >> 2) + 4 * hi);
        ao[0][r] *= fr; ao[1][r] *= fr; ao[2][r] *= fr; ao[3][r] *= fr;
      }
    }

    float rs = 0.f;
#pragma unroll
    for (int kb = 0; kb < 2; ++kb)
#pragma unroll
      for (int r = 0; r < 16; ++r) {
        float p = __builtin_amdgcn_exp2f(sc[kb][r] - mrow);
        sc[kb][r] = p;
        rs += p;
      }
    rs += __shfl_xor(rs, 32);
    lsum += rs;

    // P -> bf16 A-fragments via cvt_pk + permlane32_swap (T12)
    bf16x8_t pa[4];
#pragma unroll
    for (int kb = 0; kb < 2; ++kb) {
      uint32_t c0 = cvtpk(sc[kb][0], sc[kb][1]);
      uint32_t c1 = cvtpk(sc[kb][2], sc[kb][3]);
      uint32_t c2 = cvtpk(sc[kb][4], sc[kb][5]);
      uint32_t c3 = cvtpk(sc[kb][6], sc[kb][7]);
      uint32_t c4 = cvtpk(sc[kb][8], sc[kb][9]);
      uint32_t c5 = cvtpk(sc[kb][10], sc[kb][11]);
      uint32_t c6 = cvtpk(sc[kb][12], sc[kb][13]);
      uint32_t c7 = cvtpk(sc[kb][14], sc[kb][15]);
      plswap(c0, c2); plswap(c1, c3); plswap(c4, c6); plswap(c5, c7);
      uint4 u0 = {c0, c1, c2, c3};
      uint4 u1 = {c4, c5, c6, c7};
      pa[kb * 2]     = __builtin_bit_cast(bf16x8_t, u0);
      pa[kb * 2 + 1] = __builtin_bit_cast(bf16x8_t, u1);
    }

    // PV: O[q][d] += P(32q x 64k) . V(64k x 128d); col=d
#pragma unroll
    for (int dblk = 0; dblk < 4; ++dblk) {
      int row = dblk * 32 + l31;
      const ushort* vr = Vs + row * 64;
      int sw = (l31 & 7) << 3;
#pragma unroll
      for (int ks = 0; ks < 4; ++ks) {
        bf16x8_t vf = *(const bf16x8_t*)(vr + ((ks * 16 + hi * 8) ^ sw));
        ao[dblk] = __builtin_amdgcn_mfma_f32_32x32x16_bf16(pa[ks], vf, ao[dblk], 0, 0, 0);
      }
    }

    __syncthreads();   // drains staging vmcnt + all waves done reading cur
    cur ^= 1;
  }

  // epilogue: out[b][q][h*128 + d] = ao / lsum; C rows are q, cols are d
  float rinv = 1.0f / lsum;
#pragma unroll
  for (int r = 0; r < 16; ++r) {
    float rv = __shfl(rinv, (r & 3) + 8 * (r >> 2) + 4 * hi);
    int q = qw0 + (r & 3) + 8 * (r >> 2) + 4 * hi;
    float* og = out + (size_t)(b * S_ + q) * E_ + h * D_ + l31;
#pragma unroll
    for (int dblk = 0; dblk < 4; ++dblk)
      og[dblk * 32] = ao[dblk][r] * rv;
  }
#undef STAGE
}

extern "C" void kernel_launch(void* const* d_in, const int* in_sizes, int n_in,
                              void* d_out, int out_size, void* d_ws, size_t ws_size,
                              hipStream_t stream) {
  const float* x    = (const float*)d_in[0];
  const float* wq_w = (const float*)d_in[1];
  const float* wq_b = (const float*)d_in[2];
  const float* wk_w = (const float*)d_in[3];
  const float* wk_b = (const float*)d_in[4];
  const float* wv_w = (const float*)d_in[5];
  const float* wv_b = (const float*)d_in[6];
  const float* pos  = (const float*)d_in[7];
  float* out = (float*)d_out;

  ushort* xb  = (ushort*)d_out;                          // 33.5 MB
  ushort* wb  = (ushort*)((char*)d_out + 33554432);      // 12.6 MB
  ushort* qkv = (ushort*)d_ws;                           // 50.3 MB
  ushort* vt  = (ushort*)((char*)d_ws + 50331648);       // 8.4 MB

  k_cvt_x<<<dim3((B_ * S_ * E_) / 8 / 256), 256, 0, stream>>>(x, xb);
  dim3 tb(32, 8);
  k_cvt_w_t<<<dim3(E_ / 32, E_ / 32), tb, 0, stream>>>(wq_w, wb, E_, 0);
  k_cvt_w_t<<<dim3(KVD_ / 32, E_ / 32), tb, 0, stream>>>(wk_w, wb, KVD_, E_);
  k_cvt_w_t<<<dim3(KVD_ / 32, E_ / 32), tb, 0, stream>>>(wv_w, wb, KVD_, E_ + KVD_);
  k_gemm<<<dim3(NQKV / 128, (B_ * S_) / 128), 256, 0, stream>>>(
      xb, wb, wq_b, wk_b, wv_b, pos, qkv);
  k_v_t<<<dim3(S_ / 32, D_ / 32, B_ * HKV_), tb, 0, stream>>>(qkv, vt);
  k_attn<<<dim3(S_ / 256, B_ * H_), 512, 0, stream>>>(qkv, vt, out);
}

// Round 4
// 485.776 us; speedup vs baseline: 1.3437x; 1.0005x over previous
//
#include <hip/hip_runtime.h>
#include <hip/hip_bf16.h>
#include <cstdint>

#define B_   4
#define S_   2048
#define E_   2048
#define H_   16
#define HKV_ 4
#define D_   128
#define KVD_ 512          // HKV_*D_
#define NQKV 3072         // E_ + 2*KVD_
// softmax scale folded into Q at projection time, in base-2 units:
// 1/sqrt(128) * log2(e)
#define QSCALE 0.1275253129f

typedef __bf16 bf16x8_t __attribute__((ext_vector_type(8)));
typedef float  f32x4_t  __attribute__((ext_vector_type(4)));
typedef float  f32x16_t __attribute__((ext_vector_type(16)));

__device__ __forceinline__ ushort f2bf(float f) {
  uint32_t u = __builtin_bit_cast(uint32_t, f);
  uint32_t r = u + 0x7FFFu + ((u >> 16) & 1u);   // round-to-nearest-even
  return (ushort)(r >> 16);
}

__device__ __forceinline__ void gload16(const void* g, void* l) {
  __builtin_amdgcn_global_load_lds(
      (__attribute__((address_space(1))) void*)g,
      (__attribute__((address_space(3))) void*)l, 16, 0, 0);
}

__device__ __forceinline__ uint32_t cvtpk(float lo, float hi) {
  uint32_t r;
  asm volatile("v_cvt_pk_bf16_f32 %0, %1, %2" : "=v"(r) : "v"(lo), "v"(hi));
  return r;
}

__device__ __forceinline__ void plswap(uint32_t& a, uint32_t& b) {
  asm volatile("v_permlane32_swap_b32 %0, %1" : "+v"(a), "+v"(b));
}

// ---------------- x -> bf16 ----------------
__global__ __launch_bounds__(256) void k_cvt_x(const float* __restrict__ x,
                                               ushort* __restrict__ xb) {
  int i = blockIdx.x * 256 + threadIdx.x;          // 8 floats per thread
  const float4* p = (const float4*)x + (size_t)i * 2;
  float4 a = p[0], b = p[1];
  uint4 o;
  o.x = (uint32_t)f2bf(a.x) | ((uint32_t)f2bf(a.y) << 16);
  o.y = (uint32_t)f2bf(a.z) | ((uint32_t)f2bf(a.w) << 16);
  o.z = (uint32_t)f2bf(b.x) | ((uint32_t)f2bf(b.y) << 16);
  o.w = (uint32_t)f2bf(b.z) | ((uint32_t)f2bf(b.w) << 16);
  ((uint4*)xb)[i] = o;
}

// ------------- weight -> bf16, transposed: wb[n][k] = w[k][n] -------------
__global__ __launch_bounds__(256) void k_cvt_w_t(const float* __restrict__ w,
                                                 ushort* __restrict__ wb,
                                                 int C, int n_off) {
  __shared__ ushort t[32][33];
  int c0 = blockIdx.x * 32, r0 = blockIdx.y * 32;
  int tx = threadIdx.x, ty = threadIdx.y;          // 32 x 8
#pragma unroll
  for (int i = 0; i < 4; ++i) {
    int r = ty + i * 8;
    t[r][tx] = f2bf(w[(size_t)(r0 + r) * C + c0 + tx]);
  }
  __syncthreads();
#pragma unroll
  for (int i = 0; i < 4; ++i) {
    int c = ty + i * 8;
    wb[(size_t)(n_off + c0 + c) * E_ + r0 + tx] = t[tx][c];
  }
}

// ------------- fused QKV projection GEMM: 256x256 8-phase (m201 template) ---
// C[8192][3072] = xb[8192][2048] @ wb^T.  BM=BN=256, BK=64, 8 waves (2Mx4N).
// LDS 128KB: A[buf][half] 4x16KB @0, B[buf][half] 4x16KB @64KB.
// Half-tile = 128 rows x 64 cols bf16, XOR-swizzled 16B chunks (chunk ^= row&7)
// via pre-swizzled global source (linear gload_lds dest).
// Per tile: 4 quadrant-phases (mh,nh); counted vmcnt(6)/(8) before end-barriers.
__global__ __launch_bounds__(512, 2) void k_gemm(
    const ushort* __restrict__ xb, const ushort* __restrict__ wb,
    const float* __restrict__ wq_b, const float* __restrict__ wk_b,
    const float* __restrict__ wv_b, const float* __restrict__ pos,
    ushort* __restrict__ qkv) {
  __shared__ char ldsb[131072];
  int tid = threadIdx.x, wid = tid >> 6, lane = tid & 63;
  int l15 = lane & 15, l4 = lane >> 4;
  int wm = wid >> 2, wn = wid & 3;

  // XCD swizzle (384 = 8 * 48, bijective); tn-major chunks keep B-panel in L2
  int bid = blockIdx.x;
  bid = (bid & 7) * 48 + (bid >> 3);
  int tm = bid & 31, tn = bid >> 5;
  int m0 = tm * 256, n0 = tn * 256;

#define STAGE_A(TILE, MH)                                                      \
  {                                                                            \
    char* sb_ = ldsb + (((TILE)&1) * 32768) + ((MH) * 16384);                  \
    _Pragma("unroll") for (int i_ = 0; i_ < 2; ++i_) {                         \
      int s_ = i_ * 8 + wid;                                                   \
      int r_ = s_ * 8 + (lane >> 3);                                           \
      int cg_ = (lane & 7) ^ ((lane >> 3) & 7);                                \
      gload16(xb + (size_t)(m0 + (MH) * 128 + r_) * E_ + (TILE) * 64 + cg_ * 8,\
              sb_ + s_ * 1024);                                                \
    }                                                                          \
  }
#define STAGE_B(TILE, NH)                                                      \
  {                                                                            \
    char* sb_ = ldsb + 65536 + (((TILE)&1) * 32768) + ((NH) * 16384);          \
    _Pragma("unroll") for (int i_ = 0; i_ < 2; ++i_) {                         \
      int s_ = i_ * 8 + wid;                                                   \
      int r_ = s_ * 8 + (lane >> 3);                                           \
      int cg_ = (lane & 7) ^ ((lane >> 3) & 7);                                \
      gload16(wb + (size_t)(n0 + (NH) * 128 + r_) * E_ + (TILE) * 64 + cg_ * 8,\
              sb_ + s_ * 1024);                                                \
    }                                                                          \
  }
#define READ_A(DST, SLOT)                                                      \
  _Pragma("unroll") for (int mi_ = 0; mi_ < 4; ++mi_)                          \
  _Pragma("unroll") for (int kk_ = 0; kk_ < 2; ++kk_) {                        \
    int r_ = wm * 64 + mi_ * 16 + l15;                                         \
    int c_ = (kk_ * 4 + l4) ^ (r_ & 7);                                        \
    DST[mi_][kk_] = *(const bf16x8_t*)((SLOT) + r_ * 128 + c_ * 16);           \
  }
#define READ_B(DST, SLOT)                                                      \
  _Pragma("unroll") for (int ni_ = 0; ni_ < 2; ++ni_)                          \
  _Pragma("unroll") for (int kk_ = 0; kk_ < 2; ++kk_) {                        \
    int r_ = wn * 32 + ni_ * 16 + l15;                                         \
    int c_ = (kk_ * 4 + l4) ^ (r_ & 7);                                        \
    DST[ni_][kk_] = *(const bf16x8_t*)((SLOT) + r_ * 128 + c_ * 16);           \
  }
#define MFMA_QUAD(MH, NH, AF, BF)                                              \
  __builtin_amdgcn_s_setprio(1);                                               \
  _Pragma("unroll") for (int kk_ = 0; kk_ < 2; ++kk_)                          \
  _Pragma("unroll") for (int mi_ = 0; mi_ < 4; ++mi_)                          \
  _Pragma("unroll") for (int ni_ = 0; ni_ < 2; ++ni_)                          \
    acc[(MH) * 4 + mi_][(NH) * 2 + ni_] =                                      \
        __builtin_amdgcn_mfma_f32_16x16x32_bf16(                               \
            AF[mi_][kk_], BF[ni_][kk_], acc[(MH) * 4 + mi_][(NH) * 2 + ni_],   \
            0, 0, 0);                                                          \
  __builtin_amdgcn_s_setprio(0);
#define LGKM0()                                                                \
  asm volatile("s_waitcnt lgkmcnt(0)" ::: "memory");                           \
  __builtin_amdgcn_sched_barrier(0);
#define BAR() __builtin_amdgcn_s_barrier();

  f32x4_t acc[8][4] = {};

  const int NT = E_ / 64;   // 32
  // prologue: matches steady-state issue order; 6 half-tiles in flight
  STAGE_A(0, 0); STAGE_B(0, 0); STAGE_A(0, 1); STAGE_B(0, 1);
  STAGE_A(1, 0); STAGE_B(1, 0);
  asm volatile("s_waitcnt vmcnt(8)" ::: "memory");   // A0[0],B0[0] landed
  BAR();

  for (int t = 0; t < NT; ++t) {
    const char* Ab = ldsb + (t & 1) * 32768;
    const char* Bb = ldsb + 65536 + (t & 1) * 32768;
    bf16x8_t af[4][2], b0[2][2], b1[2][2];

    // ---- ph0: quadrant (0,0) ----
    READ_A(af, Ab);
    READ_B(b0, Bb);
    if (t + 1 < NT) STAGE_A(t + 1, 1);
    BAR(); LGKM0();
    MFMA_QUAD(0, 0, af, b0);
    asm volatile("s_waitcnt vmcnt(6)" ::: "memory");  // B1[t],A1[t] landed
    BAR();

    // ---- ph1: quadrant (0,1) ----
    READ_B(b1, Bb + 16384);
    if (t + 1 < NT) STAGE_B(t + 1, 1);
    BAR(); LGKM0();
    MFMA_QUAD(0, 1, af, b1);
    BAR();

    // ---- ph2: quadrant (1,0) ----
    READ_A(af, Ab + 16384);
    if (t + 2 < NT) STAGE_A(t + 2, 0);
    BAR(); LGKM0();
    MFMA_QUAD(1, 0, af, b0);
    BAR();

    // ---- ph3: quadrant (1,1) ----
    if (t + 2 < NT) STAGE_B(t + 2, 0);
    BAR();
    MFMA_QUAD(1, 1, af, b1);
    asm volatile("s_waitcnt vmcnt(8)" ::: "memory");  // A0[t+1],B0[t+1] landed
    BAR();
  }

  // epilogue: +bias, +pos (Q,K), *QSCALE (Q), -> bf16
#pragma unroll
  for (int mh = 0; mh < 2; ++mh)
#pragma unroll
    for (int mi = 0; mi < 4; ++mi)
#pragma unroll
      for (int nh = 0; nh < 2; ++nh)
#pragma unroll
        for (int ni = 0; ni < 2; ++ni) {
          int n = n0 + nh * 128 + wn * 32 + ni * 16 + l15;
          int mbase = m0 + mh * 128 + wm * 64 + mi * 16 + l4 * 4;
#pragma unroll
          for (int r = 0; r < 4; ++r) {
            int m = mbase + r;
            int srow = m & (S_ - 1);
            float v = acc[mh * 4 + mi][nh * 2 + ni][r];
            if (n < E_)
              v = (v + wq_b[n] + pos[(size_t)srow * E_ + n]) * QSCALE;
            else if (n < E_ + KVD_)
              v = v + wk_b[n - E_] + pos[(size_t)srow * E_ + (n - E_)];
            else
              v = v + wv_b[n - E_ - KVD_];
            qkv[(size_t)m * NQKV + n] = f2bf(v);
          }
        }
#undef STAGE_A
#undef STAGE_B
#undef READ_A
#undef READ_B
#undef MFMA_QUAD
#undef LGKM0
#undef BAR
}

// ------------- V transpose: vt[(b*4+kh)*128 + d][s] = V[b][s][kh][d] -------------
__global__ __launch_bounds__(256) void k_v_t(const ushort* __restrict__ qkv,
                                             ushort* __restrict__ vt) {
  __shared__ ushort t[32][33];
  int b = blockIdx.z >> 2, kh = blockIdx.z & 3;
  int s0 = blockIdx.x * 32, d0 = blockIdx.y * 32;
  int tx = threadIdx.x, ty = threadIdx.y;
#pragma unroll
  for (int i = 0; i < 4; ++i) {
    int s = s0 + ty + i * 8;
    t[ty + i * 8][tx] =
        qkv[(size_t)(b * S_ + s) * NQKV + E_ + KVD_ + kh * D_ + d0 + tx];
  }
  __syncthreads();
#pragma unroll
  for (int i = 0; i < 4; ++i) {
    int d = d0 + ty + i * 8;
    vt[(size_t)((b * HKV_ + kh) * D_ + d) * S_ + s0 + tx] = t[tx][ty + i * 8];
  }
}

// ------------- flash attention: m214-style 8-wave 32x32 swapped-QK -------------
__global__ __launch_bounds__(512, 2) void k_attn(const ushort* __restrict__ qkv,
                                                 const ushort* __restrict__ vt,
                                                 float* __restrict__ out) {
  __shared__ char lds[2][32768];   // per buf: Ks 16KB @0, Vs 16KB @16384
  int tid = threadIdx.x, wid = tid >> 6, lane = tid & 63;
  int l31 = lane & 31, hi = lane >> 5;
  int bh = blockIdx.y;
  int b = bh >> 4, h = bh & 15, kh = h >> 2;
  int qw0 = blockIdx.x * 256 + wid * 32;

  bf16x8_t qf[8];
  {
    const ushort* qg = qkv + (size_t)(b * S_ + qw0 + l31) * NQKV + h * D_ + hi * 8;
#pragma unroll
    for (int k = 0; k < 8; ++k) qf[k] = *(const bf16x8_t*)(qg + k * 16);
  }

  const ushort* kbase = qkv + (size_t)b * S_ * NQKV + E_ + kh * D_;
  const ushort* vbase = vt + (size_t)(b * HKV_ + kh) * D_ * S_;

  int rk0 = wid * 4 + (lane >> 4);
  int dk0 = ((lane & 15) * 8);
  int dv0 = wid * 8 + (lane >> 3);
  int kv0 = ((lane & 7) * 8);

  f32x16_t ao[4] = {};
  float mrow = -1e30f, lsum = 0.f;

#define STAGE(key0, bufp)                                                      \
  {                                                                            \
    char* bp_ = (bufp);                                                        \
    _Pragma("unroll")                                                          \
    for (int i = 0; i < 2; ++i) {                                              \
      int rk = i * 32 + rk0;                                                   \
      int dk = dk0 ^ ((rk & 7) << 3);                                          \
      gload16(kbase + (size_t)((key0) + rk) * NQKV + dk,                       \
              bp_ + i * 8192 + wid * 1024);                                    \
      int dv = i * 64 + dv0;                                                   \
      int kv = kv0 ^ ((dv & 7) << 3);                                          \
      gload16(vbase + (size_t)dv * S_ + (key0) + kv,                           \
              bp_ + 16384 + i * 8192 + wid * 1024);                            \
    }                                                                          \
  }

  STAGE(0, lds[0]);
  __syncthreads();

  int cur = 0;
  const int nt = S_ / 64;
  for (int t = 0; t < nt; ++t) {
    if (t + 1 < nt) STAGE((t + 1) * 64, lds[cur ^ 1]);

    const ushort* Ks = (const ushort*)(lds[cur]);
    const ushort* Vs = (const ushort*)(lds[cur] + 16384);

    f32x16_t sc[2] = {};
#pragma unroll
    for (int kb = 0; kb < 2; ++kb) {
      int row = kb * 32 + l31;
      const ushort* kr = Ks + row * 128;
      int sw = (l31 & 7) << 3;
#pragma unroll
      for (int ks = 0; ks < 8; ++ks) {
        bf16x8_t kf = *(const bf16x8_t*)(kr + ((ks * 16 + hi * 8) ^ sw));
        sc[kb] = __builtin_amdgcn_mfma_f32_32x32x16_bf16(kf, qf[ks], sc[kb], 0, 0, 0);
      }
    }

    float tmax = sc[0][0];
#pragma unroll
    for (int r = 1; r < 16; ++r) tmax = fmaxf(tmax, sc[0][r]);
#pragma unroll
    for (int r = 0; r < 16; ++r) tmax = fmaxf(tmax, sc[1][r]);
    tmax = fmaxf(tmax, __shfl_xor(tmax, 32));

    if (!__all(tmax - mrow <= 8.f)) {
      float mnew = fmaxf(mrow, tmax);
      float f = __builtin_amdgcn_exp2f(mrow - mnew);
      mrow = mnew;
      lsum *= f;
#pragma unroll
      for (int r = 0; r < 16; ++r) {
        float fr = __shfl(f, (r & 3) + 8 * (r >> 2) + 4 * hi);
        ao[0][r] *= fr; ao[1][r] *= fr; ao[2][r] *= fr; ao[3][r] *= fr;
      }
    }

    float rs = 0.f;
#pragma unroll
    for (int kb = 0; kb < 2; ++kb)
#pragma unroll
      for (int r = 0; r < 16; ++r) {
        float p = __builtin_amdgcn_exp2f(sc[kb][r] - mrow);
        sc[kb][r] = p;
        rs += p;
      }
    rs += __shfl_xor(rs, 32);
    lsum += rs;

    bf16x8_t pa[4];
#pragma unroll
    for (int kb = 0; kb < 2; ++kb) {
      uint32_t c0 = cvtpk(sc[kb][0], sc[kb][1]);
      uint32_t c1 = cvtpk(sc[kb][2], sc[kb][3]);
      uint32_t c2 = cvtpk(sc[kb][4], sc[kb][5]);
      uint32_t c3 = cvtpk(sc[kb][6], sc[kb][7]);
      uint32_t c4 = cvtpk(sc[kb][8], sc[kb][9]);
      uint32_t c5 = cvtpk(sc[kb][10], sc[kb][11]);
      uint32_t c6 = cvtpk(sc[kb][12], sc[kb][13]);
      uint32_t c7 = cvtpk(sc[kb][14], sc[kb][15]);
      plswap(c0, c2); plswap(c1, c3); plswap(c4, c6); plswap(c5, c7);
      uint4 u0 = {c0, c1, c2, c3};
      uint4 u1 = {c4, c5, c6, c7};
      pa[kb * 2]     = __builtin_bit_cast(bf16x8_t, u0);
      pa[kb * 2 + 1] = __builtin_bit_cast(bf16x8_t, u1);
    }

#pragma unroll
    for (int dblk = 0; dblk < 4; ++dblk) {
      int row = dblk * 32 + l31;
      const ushort* vr = Vs + row * 64;
      int sw = (l31 & 7) << 3;
#pragma unroll
      for (int ks = 0; ks < 4; ++ks) {
        bf16x8_t vf = *(const bf16x8_t*)(vr + ((ks * 16 + hi * 8) ^ sw));
        ao[dblk] = __builtin_amdgcn_mfma_f32_32x32x16_bf16(pa[ks], vf, ao[dblk], 0, 0, 0);
      }
    }

    __syncthreads();
    cur ^= 1;
  }

  float rinv = 1.0f / lsum;
#pragma unroll
  for (int r = 0; r < 16; ++r) {
    float rv = __shfl(rinv, (r & 3) + 8 * (r >> 2) + 4 * hi);
    int q = qw0 + (r & 3) + 8 * (r >> 2) + 4 * hi;
    float* og = out + (size_t)(b * S_ + q) * E_ + h * D_ + l31;
#pragma unroll
    for (int dblk = 0; dblk < 4; ++dblk)
      og[dblk * 32] = ao[dblk][r] * rv;
  }
#undef STAGE
}

extern "C" void kernel_launch(void* const* d_in, const int* in_sizes, int n_in,
                              void* d_out, int out_size, void* d_ws, size_t ws_size,
                              hipStream_t stream) {
  const float* x    = (const float*)d_in[0];
  const float* wq_w = (const float*)d_in[1];
  const float* wq_b = (const float*)d_in[2];
  const float* wk_w = (const float*)d_in[3];
  const float* wk_b = (const float*)d_in[4];
  const float* wv_w = (const float*)d_in[5];
  const float* wv_b = (const float*)d_in[6];
  const float* pos  = (const float*)d_in[7];
  float* out = (float*)d_out;

  ushort* xb  = (ushort*)d_out;                          // 33.5 MB
  ushort* wb  = (ushort*)((char*)d_out + 33554432);      // 12.6 MB
  ushort* qkv = (ushort*)d_ws;                           // 50.3 MB
  ushort* vt  = (ushort*)((char*)d_ws + 50331648);       // 8.4 MB

  k_cvt_x<<<dim3((B_ * S_ * E_) / 8 / 256), 256, 0, stream>>>(x, xb);
  dim3 tb(32, 8);
  k_cvt_w_t<<<dim3(E_ / 32, E_ / 32), tb, 0, stream>>>(wq_w, wb, E_, 0);
  k_cvt_w_t<<<dim3(KVD_ / 32, E_ / 32), tb, 0, stream>>>(wk_w, wb, KVD_, E_);
  k_cvt_w_t<<<dim3(KVD_ / 32, E_ / 32), tb, 0, stream>>>(wv_w, wb, KVD_, E_ + KVD_);
  k_gemm<<<dim3(384), 512, 0, stream>>>(xb, wb, wq_b, wk_b, wv_b, pos, qkv);
  k_v_t<<<dim3(S_ / 32, D_ / 32, B_ * HKV_), tb, 0, stream>>>(qkv, vt);
  k_attn<<<dim3(S_ / 256, B_ * H_), 512, 0, stream>>>(qkv, vt, out);
}